// Round 3
// baseline (1135.168 us; speedup 1.0000x reference)
//
#include <hip/hip_runtime.h>
#include <hip/hip_bf16.h>
#include <stdint.h>

// ---- problem constants ----
#define NB   65536      // batch points
#define NC   2
#define NV   3
#define ND   64
#define NK   1024       // codebook entries
#define NS   4
#define NH   1024
#define NL   5
#define NF   25
#define NIN  102
#define K0P  128        // padded layer-0 K

typedef __bf16 bf16x8 __attribute__((ext_vector_type(8)));
typedef float  f32x4  __attribute__((ext_vector_type(4)));

__device__ __forceinline__ void load_lds16(const void* g, void* l) {
    __builtin_amdgcn_global_load_lds(
        (const __attribute__((address_space(1))) void*)g,
        (__attribute__((address_space(3))) void*)l,
        16, 0, 0);
}

// ---------------------------------------------------------------------------
// VQ kernel: single block, 1024 threads (one codebook row per thread).
// float4 codebook loads (same sequential-d accumulation order as before:
// bitwise-identical distances), wave shfl_xor lexicographic argmin
// (associative (d,k)-min == first-index argmin), 4 syncs per stage.
// Writes idxs (as float) + loss to d_out tail, z_q_sum to workspace.
// ---------------------------------------------------------------------------
__global__ __launch_bounds__(1024) void vq_kernel(
    const float* __restrict__ latents, const int* __restrict__ latent_idx,
    const float* __restrict__ codebooks, float* __restrict__ zq_out,
    float* __restrict__ out) {
    __shared__ float zcur[ND], resid[ND], zqsum[ND], ssq[ND];
    __shared__ float sDw[16];
    __shared__ int   sKw[16];
    __shared__ int   sBest;
    int t = threadIdx.x, lane = t & 63, wv = t >> 6;
    const float* img = latents + (size_t)latent_idx[0] * (NS * ND);
    if (t < ND) { resid[t] = 0.f; zqsum[t] = 0.f; }
    __syncthreads();
    float lossAcc = 0.f;   // thread 0 only
    for (int s = 0; s < NS; s++) {
        if (t < ND) {
            float iv = img[s * ND + t];
            float r  = resid[t] + iv;
            resid[t] = r;
            zcur[t]  = (s == 0) ? iv : (r - zqsum[t]);
        }
        __syncthreads();
        // distance for codebook row t: zz - 2*dot + ee (ref formula, same
        // sequential d-order accumulation as the passing round-2 kernel)
        float zz = 0.f;
#pragma unroll
        for (int d = 0; d < ND; d++) { float z = zcur[d]; zz += z * z; }
        const float4* e4 = (const float4*)(codebooks + ((size_t)s * NK + t) * ND);
        float dot = 0.f, ee = 0.f;
#pragma unroll
        for (int i = 0; i < 16; i++) {
            float4 v = e4[i];
            dot += zcur[4 * i + 0] * v.x; dot += zcur[4 * i + 1] * v.y;
            dot += zcur[4 * i + 2] * v.z; dot += zcur[4 * i + 3] * v.w;
            ee  += v.x * v.x; ee += v.y * v.y; ee += v.z * v.z; ee += v.w * v.w;
        }
        float dmin = zz - 2.0f * dot + ee;
        int   kmin = t;
#pragma unroll
        for (int m = 1; m < 64; m <<= 1) {
            float d2 = __shfl_xor(dmin, m);
            int   k2 = __shfl_xor(kmin, m);
            if (d2 < dmin || (d2 == dmin && k2 < kmin)) { dmin = d2; kmin = k2; }
        }
        if (lane == 0) { sDw[wv] = dmin; sKw[wv] = kmin; }
        __syncthreads();
        if (t == 0) {
            float bd = sDw[0]; int bk = sKw[0];
            for (int w = 1; w < 16; w++) {
                float d2 = sDw[w]; int k2 = sKw[w];
                if (d2 < bd || (d2 == bd && k2 < bk)) { bd = d2; bk = k2; }
            }
            sBest = bk;
            out[NB * NV + s] = (float)bk;
        }
        __syncthreads();
        int best = sBest;
        const float* eb = codebooks + ((size_t)s * NK + best) * ND;
        if (t < ND) {
            float zq = eb[t];
            float d  = zq - zcur[t];
            ssq[t]   = d * d;
            zqsum[t] = zqsum[t] + (zq + (zcur[t] - zq));   // z_q_st forward (exact ref arith)
        }
        __syncthreads();
        if (t == 0) {
            float sum = 0.f;
            for (int d = 0; d < ND; d++) sum += ssq[d];
            lossAcc += 0.25f * (sum / (float)ND);
        }
    }
    if (t < ND) zq_out[t] = zqsum[t];
    if (t == 0) out[NB * NV + NS] = lossAcc;
}

// ---------------------------------------------------------------------------
// betas fused with decoder biases: bb[l][n] = sum_d zq[d]*mod_W[l][d][n]
//                                            + mod_b[l][n] + (l==0 ? b0[n] : bh[l-1][n])
// ---------------------------------------------------------------------------
__global__ __launch_bounds__(256) void betas_kernel(
    const float* __restrict__ zq, const float* __restrict__ mod_W,
    const float* __restrict__ mod_b, const float* __restrict__ b0,
    const float* __restrict__ bh, float* __restrict__ bb) {
    int g = blockIdx.x * 256 + threadIdx.x;   // < 5120
    int l = g >> 10, n = g & 1023;
    float acc = mod_b[g];
    for (int d = 0; d < ND; d++) acc += zq[d] * mod_W[(size_t)(l * ND + d) * NH + n];
    acc += (l == 0) ? b0[n] : bh[(size_t)(l - 1) * NH + n];
    bb[g] = acc;
}

// ---------------------------------------------------------------------------
// out init: values[m][v] = bout[v] (atomic-add target for the fused layer)
// ---------------------------------------------------------------------------
__global__ __launch_bounds__(256) void init_out_kernel(
    const float* __restrict__ bout, float* __restrict__ out) {
    int g = blockIdx.x * 256 + threadIdx.x;   // < NB*NV
    out[g] = bout[g % NV];
}

// ---------------------------------------------------------------------------
// Weight prep: fp32 [Ks][1024] -> bf16 transposed [1024][Kp] (zero-pad k>=Ks).
// ---------------------------------------------------------------------------
__global__ __launch_bounds__(256) void prep_kernel(
    const float* __restrict__ src, __bf16* __restrict__ dst, int Ks, int Kp) {
    __shared__ float tile[32][33];
    src += (size_t)blockIdx.z * Ks * NH;
    dst += (size_t)blockIdx.z * NH * Kp;
    int k0 = blockIdx.x * 32, n0 = blockIdx.y * 32;
    int tx = threadIdx.x, ty = threadIdx.y;   // (32, 8)
    for (int i = 0; i < 4; i++) {
        int k = k0 + ty + i * 8;
        int n = n0 + tx;
        tile[ty + i * 8][tx] = (k < Ks) ? src[(size_t)k * NH + n] : 0.0f;
    }
    __syncthreads();
    for (int i = 0; i < 4; i++) {
        int n = n0 + ty + i * 8;
        int k = k0 + tx;
        dst[(size_t)n * Kp + k] = (__bf16)tile[tx][ty + i * 8];
    }
}

// ---------------------------------------------------------------------------
// Positional encoding for a batch chunk -> bf16 [Bc][128], zero-pad 102..127.
// ---------------------------------------------------------------------------
__global__ __launch_bounds__(256) void pe_kernel(
    const float* __restrict__ coords, __bf16* __restrict__ pe) {
    int g = blockIdx.x * 256 + threadIdx.x;   // < Bc*128
    int m = g >> 7, k = g & 127;
    float v = 0.0f;
    if (k < 2) {
        v = coords[m * 2 + k];
    } else if (k < NIN) {
        int u = k - 2;
        int f = u >> 2, r = u & 3;
        float c = coords[m * 2 + (r & 1)];
        float a = c * __builtin_ldexpf(3.14159274101257324f, f);
        v = (r < 2) ? sinf(a) : cosf(a);
    }
    pe[g] = (__bf16)v;
}

// ---------------------------------------------------------------------------
// MFMA GEMM: acc = A[M][K] @ W^T[1024][K] + bb[n], bf16 in, fp32 accumulate.
// 128x128 tile, BK=32, 4 waves (2x2), 16x16x32 bf16 MFMA, global_load_lds
// width=16 staging, XOR-swizzled LDS (2-way bank alias only — free, m136).
// MODE 0: O = relu(acc) stored bf16.
// MODE 1 (final layer): out[m][v] += relu(acc) . Wout[n][v]  via shfl-reduce
//         over the 16 col-lanes + atomicAdd (out pre-initialized to bout).
// ---------------------------------------------------------------------------
template <int MODE>
__global__ __launch_bounds__(256, 2) void gemm_kernel(
    const __bf16* __restrict__ A, const __bf16* __restrict__ W,
    const float* __restrict__ bb, __bf16* __restrict__ O,
    const float* __restrict__ Wout, float* __restrict__ out, int K) {
    __shared__ __align__(16) __bf16 sA[128 * 32];
    __shared__ __align__(16) __bf16 sW[128 * 32];
    int t    = threadIdx.x;
    int bn   = blockIdx.x;            // 0..7      (N)
    int bm   = blockIdx.y;            // 0..Bc/128 (M)
    int lane = t & 63, wv = t >> 6;
    int wm   = wv >> 1, wn = wv & 1;
    int q    = lane >> 4, r16 = lane & 15;

    f32x4 acc[4][4];
    f32x4 zero = {0.f, 0.f, 0.f, 0.f};
    for (int i = 0; i < 4; i++)
        for (int j = 0; j < 4; j++) acc[i][j] = zero;

    for (int k0 = 0; k0 < K; k0 += 32) {
#pragma unroll
        for (int p = 0; p < 2; p++) {
            int i  = p * 256 + t;
            int r  = i >> 2;
            int cg = (i & 3) ^ ((r >> 1) & 3);     // swizzled source chunk
            const __bf16* gA = A + ((size_t)(bm * 128 + r) * K + (size_t)(k0 + cg * 8));
            load_lds16((const void*)gA, (void*)((char*)sA + i * 16));
            const __bf16* gW = W + ((size_t)(bn * 128 + r) * K + (size_t)(k0 + cg * 8));
            load_lds16((const void*)gW, (void*)((char*)sW + i * 16));
        }
        __syncthreads();

        bf16x8 af[4], bfr[4];
#pragma unroll
        for (int i = 0; i < 4; i++) {
            int rowA = wm * 64 + i * 16 + r16;
            int chA  = rowA * 4 + (q ^ ((rowA >> 1) & 3));
            af[i]    = *(const bf16x8*)(sA + chA * 8);
            int rowB = wn * 64 + i * 16 + r16;
            int chB  = rowB * 4 + (q ^ ((rowB >> 1) & 3));
            bfr[i]   = *(const bf16x8*)(sW + chB * 8);
        }
#pragma unroll
        for (int i = 0; i < 4; i++)
#pragma unroll
            for (int j = 0; j < 4; j++)
                acc[i][j] = __builtin_amdgcn_mfma_f32_16x16x32_bf16(af[i], bfr[j], acc[i][j], 0, 0, 0);
        __syncthreads();
    }

    // epilogue: C/D layout col=lane&15, row=(lane>>4)*4+reg
    if constexpr (MODE == 0) {
#pragma unroll
        for (int i = 0; i < 4; i++) {
            int mbase = bm * 128 + wm * 64 + i * 16 + q * 4;
#pragma unroll
            for (int j = 0; j < 4; j++) {
                int n = bn * 128 + wn * 64 + j * 16 + r16;
                float bias = bb[n];
#pragma unroll
                for (int r = 0; r < 4; r++) {
                    float val = fmaxf(acc[i][j][r] + bias, 0.0f);
                    O[(size_t)(mbase + r) * NH + n] = (__bf16)val;
                }
            }
        }
    } else {
#pragma unroll
        for (int i = 0; i < 4; i++) {
            float p0[4] = {0.f, 0.f, 0.f, 0.f};
            float p1[4] = {0.f, 0.f, 0.f, 0.f};
            float p2[4] = {0.f, 0.f, 0.f, 0.f};
#pragma unroll
            for (int j = 0; j < 4; j++) {
                int n = bn * 128 + wn * 64 + j * 16 + r16;
                float bias = bb[n];
                float w0 = Wout[n * NV + 0], w1 = Wout[n * NV + 1], w2 = Wout[n * NV + 2];
#pragma unroll
                for (int r = 0; r < 4; r++) {
                    float val = fmaxf(acc[i][j][r] + bias, 0.0f);
                    p0[r] += val * w0; p1[r] += val * w1; p2[r] += val * w2;
                }
            }
            // reduce over the 16 col-lanes (masks <16 stay within q-group)
#pragma unroll
            for (int m = 1; m < 16; m <<= 1) {
#pragma unroll
                for (int r = 0; r < 4; r++) {
                    p0[r] += __shfl_xor(p0[r], m);
                    p1[r] += __shfl_xor(p1[r], m);
                    p2[r] += __shfl_xor(p2[r], m);
                }
            }
            if (r16 == 0) {
                int mbase = bm * 128 + wm * 64 + i * 16 + q * 4;
#pragma unroll
                for (int r = 0; r < 4; r++) {
                    atomicAdd(&out[(size_t)(mbase + r) * NV + 0], p0[r]);
                    atomicAdd(&out[(size_t)(mbase + r) * NV + 1], p1[r]);
                    atomicAdd(&out[(size_t)(mbase + r) * NV + 2], p2[r]);
                }
            }
        }
    }
}

// ---------------------------------------------------------------------------
extern "C" void kernel_launch(void* const* d_in, const int* in_sizes, int n_in,
                              void* d_out, int out_size, void* d_ws, size_t ws_size,
                              hipStream_t stream) {
    const float* coords     = (const float*)d_in[0];
    const int*   latent_idx = (const int*)d_in[1];
    const float* latents    = (const float*)d_in[2];
    const float* codebooks  = (const float*)d_in[3];
    const float* mod_W      = (const float*)d_in[4];
    const float* mod_b      = (const float*)d_in[5];
    const float* dec_W0     = (const float*)d_in[6];
    const float* dec_b0     = (const float*)d_in[7];
    const float* dec_Wh     = (const float*)d_in[8];
    const float* dec_bh     = (const float*)d_in[9];
    const float* dec_Wout   = (const float*)d_in[10];
    const float* dec_bout   = (const float*)d_in[11];
    float* out = (float*)d_out;

    // ---- workspace layout (fixed part ~8.67 MB) ----
    char* wsb = (char*)d_ws;
    float*  zq  = (float*)(wsb + 0);                       //      256 B
    float*  bb  = (float*)(wsb + 256);                     //   20,480 B
    __bf16* W0T = (__bf16*)(wsb + 20736);                  //  262,144 B  [1024][128]
    __bf16* WhT = (__bf16*)(wsb + 282880);                 // 8,388,608 B [4][1024][1024]
    const size_t fixed_end = 8671488;

    // adaptive chunk: cap 32768 (ws ~137 MB), halve until it fits ws_size.
    // Deterministic in ws_size -> identical launch sequence (capture-safe).
    int Bc = 32768;
    while (Bc > 256 && fixed_end + 2 * (size_t)Bc * NH * sizeof(__bf16) > ws_size)
        Bc >>= 1;

    __bf16* hA = (__bf16*)(wsb + fixed_end);               // [Bc][1024]
    __bf16* hB = hA + (size_t)Bc * NH;                     // [Bc][1024]
    __bf16* pe = hB;   // pe [Bc][128] aliases hB (dead before layer-1 writes hB)

    // ---- one-time (per call) small kernels ----
    vq_kernel<<<1, 1024, 0, stream>>>(latents, latent_idx, codebooks, zq, out);
    betas_kernel<<<20, 256, 0, stream>>>(zq, mod_W, mod_b, dec_b0, dec_bh, bb);
    init_out_kernel<<<(NB * NV) / 256, 256, 0, stream>>>(dec_bout, out);
    prep_kernel<<<dim3(4, 32, 1), dim3(32, 8), 0, stream>>>(dec_W0, W0T, NIN, K0P);
    prep_kernel<<<dim3(32, 32, 4), dim3(32, 8), 0, stream>>>(dec_Wh, WhT, NH, NH);

    // ---- chunked 5-layer MLP, output layer fused into the last GEMM ----
    for (int c0 = 0; c0 < NB; c0 += Bc) {
        pe_kernel<<<(Bc * 128) / 256, 256, 0, stream>>>(coords + (size_t)c0 * NC, pe);
        gemm_kernel<0><<<dim3(8, Bc / 128), 256, 0, stream>>>(
            pe, W0T, bb + 0 * NH, hA, nullptr, nullptr, K0P);
        gemm_kernel<0><<<dim3(8, Bc / 128), 256, 0, stream>>>(
            hA, WhT + 0 * (size_t)NH * NH, bb + 1 * NH, hB, nullptr, nullptr, NH);
        gemm_kernel<0><<<dim3(8, Bc / 128), 256, 0, stream>>>(
            hB, WhT + 1 * (size_t)NH * NH, bb + 2 * NH, hA, nullptr, nullptr, NH);
        gemm_kernel<0><<<dim3(8, Bc / 128), 256, 0, stream>>>(
            hA, WhT + 2 * (size_t)NH * NH, bb + 3 * NH, hB, nullptr, nullptr, NH);
        gemm_kernel<1><<<dim3(8, Bc / 128), 256, 0, stream>>>(
            hB, WhT + 3 * (size_t)NH * NH, bb + 4 * NH, nullptr,
            dec_Wout, out + (size_t)c0 * NV, NH);
    }
}

// Round 4
// 948.774 us; speedup vs baseline: 1.1965x; 1.1965x over previous
//
#include <hip/hip_runtime.h>
#include <hip/hip_bf16.h>
#include <stdint.h>

// ---- problem constants ----
#define NB   65536      // batch points
#define NC   2
#define NV   3
#define ND   64
#define NK   1024       // codebook entries
#define NS   4
#define NH   1024
#define NL   5
#define NF   25
#define NIN  102
#define K0P  128        // padded layer-0 K

typedef __bf16 bf16x8 __attribute__((ext_vector_type(8)));
typedef __bf16 bf16x4 __attribute__((ext_vector_type(4)));
typedef float  f32x4  __attribute__((ext_vector_type(4)));

__device__ __forceinline__ void load_lds16(const void* g, void* l) {
    __builtin_amdgcn_global_load_lds(
        (const __attribute__((address_space(1))) void*)g,
        (__attribute__((address_space(3))) void*)l,
        16, 0, 0);
}

// ---------------------------------------------------------------------------
// VQ kernel: single block, 1024 threads (one codebook row per thread).
// float4 codebook loads, wave shfl_xor lexicographic argmin (== first-index
// argmin). Writes idxs (as float) + loss to d_out tail, z_q_sum to workspace.
// ---------------------------------------------------------------------------
__global__ __launch_bounds__(1024) void vq_kernel(
    const float* __restrict__ latents, const int* __restrict__ latent_idx,
    const float* __restrict__ codebooks, float* __restrict__ zq_out,
    float* __restrict__ out) {
    __shared__ float zcur[ND], resid[ND], zqsum[ND], ssq[ND];
    __shared__ float sDw[16];
    __shared__ int   sKw[16];
    __shared__ int   sBest;
    int t = threadIdx.x, lane = t & 63, wv = t >> 6;
    const float* img = latents + (size_t)latent_idx[0] * (NS * ND);
    if (t < ND) { resid[t] = 0.f; zqsum[t] = 0.f; }
    __syncthreads();
    float lossAcc = 0.f;   // thread 0 only
    for (int s = 0; s < NS; s++) {
        if (t < ND) {
            float iv = img[s * ND + t];
            float r  = resid[t] + iv;
            resid[t] = r;
            zcur[t]  = (s == 0) ? iv : (r - zqsum[t]);
        }
        __syncthreads();
        float zz = 0.f;
#pragma unroll
        for (int d = 0; d < ND; d++) { float z = zcur[d]; zz += z * z; }
        const float4* e4 = (const float4*)(codebooks + ((size_t)s * NK + t) * ND);
        float dot = 0.f, ee = 0.f;
#pragma unroll
        for (int i = 0; i < 16; i++) {
            float4 v = e4[i];
            dot += zcur[4 * i + 0] * v.x; dot += zcur[4 * i + 1] * v.y;
            dot += zcur[4 * i + 2] * v.z; dot += zcur[4 * i + 3] * v.w;
            ee  += v.x * v.x; ee += v.y * v.y; ee += v.z * v.z; ee += v.w * v.w;
        }
        float dmin = zz - 2.0f * dot + ee;
        int   kmin = t;
#pragma unroll
        for (int m = 1; m < 64; m <<= 1) {
            float d2 = __shfl_xor(dmin, m);
            int   k2 = __shfl_xor(kmin, m);
            if (d2 < dmin || (d2 == dmin && k2 < kmin)) { dmin = d2; kmin = k2; }
        }
        if (lane == 0) { sDw[wv] = dmin; sKw[wv] = kmin; }
        __syncthreads();
        if (t == 0) {
            float bd = sDw[0]; int bk = sKw[0];
            for (int w = 1; w < 16; w++) {
                float d2 = sDw[w]; int k2 = sKw[w];
                if (d2 < bd || (d2 == bd && k2 < bk)) { bd = d2; bk = k2; }
            }
            sBest = bk;
            out[NB * NV + s] = (float)bk;
        }
        __syncthreads();
        int best = sBest;
        const float* eb = codebooks + ((size_t)s * NK + best) * ND;
        if (t < ND) {
            float zq = eb[t];
            float d  = zq - zcur[t];
            ssq[t]   = d * d;
            zqsum[t] = zqsum[t] + (zq + (zcur[t] - zq));   // z_q_st forward (exact ref arith)
        }
        __syncthreads();
        if (t == 0) {
            float sum = 0.f;
            for (int d = 0; d < ND; d++) sum += ssq[d];
            lossAcc += 0.25f * (sum / (float)ND);
        }
    }
    if (t < ND) zq_out[t] = zqsum[t];
    if (t == 0) out[NB * NV + NS] = lossAcc;
}

// ---------------------------------------------------------------------------
// betas fused with decoder biases
// ---------------------------------------------------------------------------
__global__ __launch_bounds__(256) void betas_kernel(
    const float* __restrict__ zq, const float* __restrict__ mod_W,
    const float* __restrict__ mod_b, const float* __restrict__ b0,
    const float* __restrict__ bh, float* __restrict__ bb) {
    int g = blockIdx.x * 256 + threadIdx.x;   // < 5120
    int l = g >> 10, n = g & 1023;
    float acc = mod_b[g];
    for (int d = 0; d < ND; d++) acc += zq[d] * mod_W[(size_t)(l * ND + d) * NH + n];
    acc += (l == 0) ? b0[n] : bh[(size_t)(l - 1) * NH + n];
    bb[g] = acc;
}

// ---------------------------------------------------------------------------
// out init: values[m][v] = bout[v] (atomic-add target for the fused layer)
// ---------------------------------------------------------------------------
__global__ __launch_bounds__(256) void init_out_kernel(
    const float* __restrict__ bout, float* __restrict__ out) {
    int g = blockIdx.x * 256 + threadIdx.x;   // < NB*NV
    out[g] = bout[g % NV];
}

// ---------------------------------------------------------------------------
// Weight prep: fp32 [Ks][1024] -> bf16 transposed [1024][Kp] (zero-pad k>=Ks)
// ---------------------------------------------------------------------------
__global__ __launch_bounds__(256) void prep_kernel(
    const float* __restrict__ src, __bf16* __restrict__ dst, int Ks, int Kp) {
    __shared__ float tile[32][33];
    src += (size_t)blockIdx.z * Ks * NH;
    dst += (size_t)blockIdx.z * NH * Kp;
    int k0 = blockIdx.x * 32, n0 = blockIdx.y * 32;
    int tx = threadIdx.x, ty = threadIdx.y;   // (32, 8)
    for (int i = 0; i < 4; i++) {
        int k = k0 + ty + i * 8;
        int n = n0 + tx;
        tile[ty + i * 8][tx] = (k < Ks) ? src[(size_t)k * NH + n] : 0.0f;
    }
    __syncthreads();
    for (int i = 0; i < 4; i++) {
        int n = n0 + ty + i * 8;
        int k = k0 + tx;
        dst[(size_t)n * Kp + k] = (__bf16)tile[tx][ty + i * 8];
    }
}

// ---------------------------------------------------------------------------
// Positional encoding for a batch chunk -> bf16 [Bc][128], zero-pad 102..127
// ---------------------------------------------------------------------------
__global__ __launch_bounds__(256) void pe_kernel(
    const float* __restrict__ coords, __bf16* __restrict__ pe) {
    int g = blockIdx.x * 256 + threadIdx.x;   // < Bc*128
    int m = g >> 7, k = g & 127;
    float v = 0.0f;
    if (k < 2) {
        v = coords[m * 2 + k];
    } else if (k < NIN) {
        int u = k - 2;
        int f = u >> 2, r = u & 3;
        float c = coords[m * 2 + (r & 1)];
        float a = c * __builtin_ldexpf(3.14159274101257324f, f);
        v = (r < 2) ? sinf(a) : cosf(a);
    }
    pe[g] = (__bf16)v;
}

// ---------------------------------------------------------------------------
// MFMA GEMM: acc = A[M][K] @ W^T[1024][K] + bb[n], bf16 in, fp32 accumulate.
// 128x128 tile, BK=32, 4 waves (2x2), 16x16x32 bf16 MFMA, global_load_lds
// width=16 staging, XOR-swizzled LDS (2-way bank alias only — free, m136).
//
// Grid is 1D (8*Mb blocks) with an XCD-aware decode: xcd = fid&7 (matches
// assumed round-robin block->XCD assignment), each XCD residue owns a
// contiguous bm range and enumerates bn fastest -> the 8 blocks sharing an
// A-tile stay on ONE XCD; in-flight A window ~3MB + W 2MB ~ per-XCD L2.
//
// MFMA operands are SWAPPED (D = W_frag x A_frag, i.e. D^T of the usual):
// lane's 4 acc regs = 4 consecutive n at fixed m -> packed 8B bf16x4 stores.
// MODE 0: O = relu(acc+bb) stored bf16 (16 dwordx2 stores/lane).
// MODE 1: out[m][v] += relu(acc+bb).Wout[n][v], q-lane shfl reduce + atomicAdd
//         (out pre-initialized to bout).
// ---------------------------------------------------------------------------
template <int MODE>
__global__ __launch_bounds__(256, 2) void gemm_kernel(
    const __bf16* __restrict__ A, const __bf16* __restrict__ W,
    const float* __restrict__ bb, __bf16* __restrict__ O,
    const float* __restrict__ Wout, float* __restrict__ out, int K, int Mb) {
    __shared__ __align__(16) __bf16 sA[128 * 32];
    __shared__ __align__(16) __bf16 sW[128 * 32];
    int t   = threadIdx.x;
    int fid = blockIdx.x;
    int xcd = fid & 7;
    int j8  = fid >> 3;                 // 0..Mb-1
    int bn  = j8 & 7;                   // fastest within an XCD
    int bm  = xcd * (Mb >> 3) + (j8 >> 3);
    int lane = t & 63, wv = t >> 6;
    int wm   = wv >> 1, wn = wv & 1;
    int q    = lane >> 4, r16 = lane & 15;

    f32x4 acc[4][4];
    f32x4 zero = {0.f, 0.f, 0.f, 0.f};
    for (int i = 0; i < 4; i++)
        for (int j = 0; j < 4; j++) acc[i][j] = zero;

    for (int k0 = 0; k0 < K; k0 += 32) {
#pragma unroll
        for (int p = 0; p < 2; p++) {
            int i  = p * 256 + t;
            int r  = i >> 2;
            int cg = (i & 3) ^ ((r >> 1) & 3);     // swizzled source chunk
            const __bf16* gA = A + ((size_t)(bm * 128 + r) * K + (size_t)(k0 + cg * 8));
            load_lds16((const void*)gA, (void*)((char*)sA + i * 16));
            const __bf16* gW = W + ((size_t)(bn * 128 + r) * K + (size_t)(k0 + cg * 8));
            load_lds16((const void*)gW, (void*)((char*)sW + i * 16));
        }
        __syncthreads();

        bf16x8 af[4], bfr[4];
#pragma unroll
        for (int i = 0; i < 4; i++) {
            int rowA = wm * 64 + i * 16 + r16;
            int chA  = rowA * 4 + (q ^ ((rowA >> 1) & 3));
            af[i]    = *(const bf16x8*)(sA + chA * 8);
            int rowB = wn * 64 + i * 16 + r16;
            int chB  = rowB * 4 + (q ^ ((rowB >> 1) & 3));
            bfr[i]   = *(const bf16x8*)(sW + chB * 8);
        }
        // swapped operands: acc[i][j] rows (q*4+r) = n-dim(j), cols (r16) = m-dim(i)
#pragma unroll
        for (int i = 0; i < 4; i++)
#pragma unroll
            for (int j = 0; j < 4; j++)
                acc[i][j] = __builtin_amdgcn_mfma_f32_16x16x32_bf16(bfr[j], af[i], acc[i][j], 0, 0, 0);
        __syncthreads();
    }

    // lane element (i,j,r):  m = bm*128+wm*64+i*16+r16,  n = bn*128+wn*64+j*16+q*4+r
    if constexpr (MODE == 0) {
#pragma unroll
        for (int j = 0; j < 4; j++) {
            int nb = bn * 128 + wn * 64 + j * 16 + q * 4;
            f32x4 b4 = *(const f32x4*)(bb + nb);
#pragma unroll
            for (int i = 0; i < 4; i++) {
                int m = bm * 128 + wm * 64 + i * 16 + r16;
                bf16x4 o4;
#pragma unroll
                for (int r = 0; r < 4; r++)
                    o4[r] = (__bf16)fmaxf(acc[i][j][r] + b4[r], 0.0f);
                *(bf16x4*)(O + (size_t)m * NH + nb) = o4;
            }
        }
    } else {
#pragma unroll
        for (int i = 0; i < 4; i++) {
            float p0 = 0.f, p1 = 0.f, p2 = 0.f;
#pragma unroll
            for (int j = 0; j < 4; j++) {
                int nb = bn * 128 + wn * 64 + j * 16 + q * 4;
                f32x4 b4 = *(const f32x4*)(bb + nb);
#pragma unroll
                for (int r = 0; r < 4; r++) {
                    float val = fmaxf(acc[i][j][r] + b4[r], 0.0f);
                    const float* w = Wout + (size_t)(nb + r) * NV;
                    p0 += val * w[0]; p1 += val * w[1]; p2 += val * w[2];
                }
            }
            // reduce over the 4 q-lanes (lane bits 4,5) holding the same m
            p0 += __shfl_xor(p0, 16); p0 += __shfl_xor(p0, 32);
            p1 += __shfl_xor(p1, 16); p1 += __shfl_xor(p1, 32);
            p2 += __shfl_xor(p2, 16); p2 += __shfl_xor(p2, 32);
            if (q == 0) {
                int m = bm * 128 + wm * 64 + i * 16 + r16;
                atomicAdd(&out[(size_t)m * NV + 0], p0);
                atomicAdd(&out[(size_t)m * NV + 1], p1);
                atomicAdd(&out[(size_t)m * NV + 2], p2);
            }
        }
    }
}

// ---------------------------------------------------------------------------
extern "C" void kernel_launch(void* const* d_in, const int* in_sizes, int n_in,
                              void* d_out, int out_size, void* d_ws, size_t ws_size,
                              hipStream_t stream) {
    const float* coords     = (const float*)d_in[0];
    const int*   latent_idx = (const int*)d_in[1];
    const float* latents    = (const float*)d_in[2];
    const float* codebooks  = (const float*)d_in[3];
    const float* mod_W      = (const float*)d_in[4];
    const float* mod_b      = (const float*)d_in[5];
    const float* dec_W0     = (const float*)d_in[6];
    const float* dec_b0     = (const float*)d_in[7];
    const float* dec_Wh     = (const float*)d_in[8];
    const float* dec_bh     = (const float*)d_in[9];
    const float* dec_Wout   = (const float*)d_in[10];
    const float* dec_bout   = (const float*)d_in[11];
    float* out = (float*)d_out;

    // ---- workspace layout (fixed part ~8.67 MB) ----
    char* wsb = (char*)d_ws;
    float*  zq  = (float*)(wsb + 0);                       //      256 B
    float*  bb  = (float*)(wsb + 256);                     //   20,480 B
    __bf16* W0T = (__bf16*)(wsb + 20736);                  //  262,144 B  [1024][128]
    __bf16* WhT = (__bf16*)(wsb + 282880);                 // 8,388,608 B [4][1024][1024]
    const size_t fixed_end = 8671488;

    // adaptive chunk: cap 32768, halve until fits; floor 1024 so Mb%8==0.
    // Deterministic in ws_size -> identical launch sequence (capture-safe).
    int Bc = 32768;
    while (Bc > 1024 && fixed_end + 2 * (size_t)Bc * NH * sizeof(__bf16) > ws_size)
        Bc >>= 1;
    int Mb = Bc / 128;

    __bf16* hA = (__bf16*)(wsb + fixed_end);               // [Bc][1024]
    __bf16* hB = hA + (size_t)Bc * NH;                     // [Bc][1024]
    __bf16* pe = hB;   // pe [Bc][128] aliases hB (dead before layer-1 writes hB)

    // ---- one-time (per call) small kernels ----
    vq_kernel<<<1, 1024, 0, stream>>>(latents, latent_idx, codebooks, zq, out);
    betas_kernel<<<20, 256, 0, stream>>>(zq, mod_W, mod_b, dec_b0, dec_bh, bb);
    init_out_kernel<<<(NB * NV) / 256, 256, 0, stream>>>(dec_bout, out);
    prep_kernel<<<dim3(4, 32, 1), dim3(32, 8), 0, stream>>>(dec_W0, W0T, NIN, K0P);
    prep_kernel<<<dim3(32, 32, 4), dim3(32, 8), 0, stream>>>(dec_Wh, WhT, NH, NH);

    // ---- chunked 5-layer MLP, output layer fused into the last GEMM ----
    for (int c0 = 0; c0 < NB; c0 += Bc) {
        pe_kernel<<<(Bc * 128) / 256, 256, 0, stream>>>(coords + (size_t)c0 * NC, pe);
        gemm_kernel<0><<<8 * Mb, 256, 0, stream>>>(
            pe, W0T, bb + 0 * NH, hA, nullptr, nullptr, K0P, Mb);
        gemm_kernel<0><<<8 * Mb, 256, 0, stream>>>(
            hA, WhT + 0 * (size_t)NH * NH, bb + 1 * NH, hB, nullptr, nullptr, NH, Mb);
        gemm_kernel<0><<<8 * Mb, 256, 0, stream>>>(
            hB, WhT + 1 * (size_t)NH * NH, bb + 2 * NH, hA, nullptr, nullptr, NH, Mb);
        gemm_kernel<0><<<8 * Mb, 256, 0, stream>>>(
            hA, WhT + 2 * (size_t)NH * NH, bb + 3 * NH, hB, nullptr, nullptr, NH, Mb);
        gemm_kernel<1><<<8 * Mb, 256, 0, stream>>>(
            hB, WhT + 3 * (size_t)NH * NH, bb + 4 * NH, nullptr,
            dec_Wout, out + (size_t)c0 * NV, NH, Mb);
    }
}

// Round 5
// 946.473 us; speedup vs baseline: 1.1994x; 1.0024x over previous
//
#include <hip/hip_runtime.h>
#include <hip/hip_bf16.h>
#include <stdint.h>

// ---- problem constants ----
#define NB   65536      // batch points
#define NC   2
#define NV   3
#define ND   64
#define NK   1024       // codebook entries
#define NS   4
#define NH   1024
#define NL   5
#define NF   25
#define NIN  102
#define K0P  128        // padded layer-0 K

typedef __bf16 bf16x8 __attribute__((ext_vector_type(8)));
typedef __bf16 bf16x4 __attribute__((ext_vector_type(4)));
typedef float  f32x4  __attribute__((ext_vector_type(4)));

__device__ __forceinline__ void load_lds16(const void* g, void* l) {
    __builtin_amdgcn_global_load_lds(
        (const __attribute__((address_space(1))) void*)g,
        (__attribute__((address_space(3))) void*)l,
        16, 0, 0);
}

// ---------------------------------------------------------------------------
// VQ kernel: single block, 1024 threads (one codebook row per thread).
// ---------------------------------------------------------------------------
__global__ __launch_bounds__(1024) void vq_kernel(
    const float* __restrict__ latents, const int* __restrict__ latent_idx,
    const float* __restrict__ codebooks, float* __restrict__ zq_out,
    float* __restrict__ out) {
    __shared__ float zcur[ND], resid[ND], zqsum[ND], ssq[ND];
    __shared__ float sDw[16];
    __shared__ int   sKw[16];
    __shared__ int   sBest;
    int t = threadIdx.x, lane = t & 63, wv = t >> 6;
    const float* img = latents + (size_t)latent_idx[0] * (NS * ND);
    if (t < ND) { resid[t] = 0.f; zqsum[t] = 0.f; }
    __syncthreads();
    float lossAcc = 0.f;   // thread 0 only
    for (int s = 0; s < NS; s++) {
        if (t < ND) {
            float iv = img[s * ND + t];
            float r  = resid[t] + iv;
            resid[t] = r;
            zcur[t]  = (s == 0) ? iv : (r - zqsum[t]);
        }
        __syncthreads();
        float zz = 0.f;
#pragma unroll
        for (int d = 0; d < ND; d++) { float z = zcur[d]; zz += z * z; }
        const float4* e4 = (const float4*)(codebooks + ((size_t)s * NK + t) * ND);
        float dot = 0.f, ee = 0.f;
#pragma unroll
        for (int i = 0; i < 16; i++) {
            float4 v = e4[i];
            dot += zcur[4 * i + 0] * v.x; dot += zcur[4 * i + 1] * v.y;
            dot += zcur[4 * i + 2] * v.z; dot += zcur[4 * i + 3] * v.w;
            ee  += v.x * v.x; ee += v.y * v.y; ee += v.z * v.z; ee += v.w * v.w;
        }
        float dmin = zz - 2.0f * dot + ee;
        int   kmin = t;
#pragma unroll
        for (int m = 1; m < 64; m <<= 1) {
            float d2 = __shfl_xor(dmin, m);
            int   k2 = __shfl_xor(kmin, m);
            if (d2 < dmin || (d2 == dmin && k2 < kmin)) { dmin = d2; kmin = k2; }
        }
        if (lane == 0) { sDw[wv] = dmin; sKw[wv] = kmin; }
        __syncthreads();
        if (t == 0) {
            float bd = sDw[0]; int bk = sKw[0];
            for (int w = 1; w < 16; w++) {
                float d2 = sDw[w]; int k2 = sKw[w];
                if (d2 < bd || (d2 == bd && k2 < bk)) { bd = d2; bk = k2; }
            }
            sBest = bk;
            out[NB * NV + s] = (float)bk;
        }
        __syncthreads();
        int best = sBest;
        const float* eb = codebooks + ((size_t)s * NK + best) * ND;
        if (t < ND) {
            float zq = eb[t];
            float d  = zq - zcur[t];
            ssq[t]   = d * d;
            zqsum[t] = zqsum[t] + (zq + (zcur[t] - zq));   // z_q_st forward (exact ref arith)
        }
        __syncthreads();
        if (t == 0) {
            float sum = 0.f;
            for (int d = 0; d < ND; d++) sum += ssq[d];
            lossAcc += 0.25f * (sum / (float)ND);
        }
    }
    if (t < ND) zq_out[t] = zqsum[t];
    if (t == 0) out[NB * NV + NS] = lossAcc;
}

// ---------------------------------------------------------------------------
// betas fused with decoder biases
// ---------------------------------------------------------------------------
__global__ __launch_bounds__(256) void betas_kernel(
    const float* __restrict__ zq, const float* __restrict__ mod_W,
    const float* __restrict__ mod_b, const float* __restrict__ b0,
    const float* __restrict__ bh, float* __restrict__ bb) {
    int g = blockIdx.x * 256 + threadIdx.x;   // < 5120
    int l = g >> 10, n = g & 1023;
    float acc = mod_b[g];
    for (int d = 0; d < ND; d++) acc += zq[d] * mod_W[(size_t)(l * ND + d) * NH + n];
    acc += (l == 0) ? b0[n] : bh[(size_t)(l - 1) * NH + n];
    bb[g] = acc;
}

// ---------------------------------------------------------------------------
// out init: values[m][v] = bout[v] (atomic-add target for the fused layer)
// ---------------------------------------------------------------------------
__global__ __launch_bounds__(256) void init_out_kernel(
    const float* __restrict__ bout, float* __restrict__ out) {
    int g = blockIdx.x * 256 + threadIdx.x;   // < NB*NV
    out[g] = bout[g % NV];
}

// ---------------------------------------------------------------------------
// Weight prep: fp32 [Ks][1024] -> bf16 transposed [1024][Kp] (zero-pad k>=Ks)
// ---------------------------------------------------------------------------
__global__ __launch_bounds__(256) void prep_kernel(
    const float* __restrict__ src, __bf16* __restrict__ dst, int Ks, int Kp) {
    __shared__ float tile[32][33];
    src += (size_t)blockIdx.z * Ks * NH;
    dst += (size_t)blockIdx.z * NH * Kp;
    int k0 = blockIdx.x * 32, n0 = blockIdx.y * 32;
    int tx = threadIdx.x, ty = threadIdx.y;   // (32, 8)
    for (int i = 0; i < 4; i++) {
        int k = k0 + ty + i * 8;
        int n = n0 + tx;
        tile[ty + i * 8][tx] = (k < Ks) ? src[(size_t)k * NH + n] : 0.0f;
    }
    __syncthreads();
    for (int i = 0; i < 4; i++) {
        int n = n0 + ty + i * 8;
        int k = k0 + tx;
        dst[(size_t)n * Kp + k] = (__bf16)tile[tx][ty + i * 8];
    }
}

// ---------------------------------------------------------------------------
// Positional encoding for a batch chunk -> bf16 [Bc][128], zero-pad 102..127
// ---------------------------------------------------------------------------
__global__ __launch_bounds__(256) void pe_kernel(
    const float* __restrict__ coords, __bf16* __restrict__ pe) {
    int g = blockIdx.x * 256 + threadIdx.x;   // < Bc*128
    int m = g >> 7, k = g & 127;
    float v = 0.0f;
    if (k < 2) {
        v = coords[m * 2 + k];
    } else if (k < NIN) {
        int u = k - 2;
        int f = u >> 2, r = u & 3;
        float c = coords[m * 2 + (r & 1)];
        float a = c * __builtin_ldexpf(3.14159274101257324f, f);
        v = (r < 2) ? sinf(a) : cosf(a);
    }
    pe[g] = (__bf16)v;
}

// ---------------------------------------------------------------------------
// MFMA GEMM: acc = A[M][K] @ W^T[1024][K] + bb[n], bf16 in, fp32 accumulate.
// 128x128 tile, BK=32, 4 waves (2x2), 16x16x32 bf16 MFMA, global_load_lds
// width=16 staging, XOR-swizzled LDS (2-way bank alias only — free, m136).
// XCD-residue grid decode (verified R4: FETCH 265->53 MB).
// __launch_bounds__(256, 4): cap unified VGPR+AGPR at 128/lane -> 16 waves/CU
// (R4 ran 132 regs -> 3 waves/SIMD, occupancy 28%, MfmaUtil 25%).
// ---------------------------------------------------------------------------
template <int MODE>
__global__ __launch_bounds__(256, 4) void gemm_kernel(
    const __bf16* __restrict__ A, const __bf16* __restrict__ W,
    const float* __restrict__ bb, __bf16* __restrict__ O,
    const float* __restrict__ Wout, float* __restrict__ out, int K, int Mb) {
    __shared__ __align__(16) __bf16 sA[128 * 32];
    __shared__ __align__(16) __bf16 sW[128 * 32];
    int t   = threadIdx.x;
    int fid = blockIdx.x;
    int xcd = fid & 7;
    int j8  = fid >> 3;                 // 0..Mb-1
    int bn  = j8 & 7;                   // fastest within an XCD
    int bm  = xcd * (Mb >> 3) + (j8 >> 3);
    int lane = t & 63, wv = t >> 6;
    int wm   = wv >> 1, wn = wv & 1;
    int q    = lane >> 4, r16 = lane & 15;

    f32x4 acc[4][4];
    f32x4 zero = {0.f, 0.f, 0.f, 0.f};
    for (int i = 0; i < 4; i++)
        for (int j = 0; j < 4; j++) acc[i][j] = zero;

    for (int k0 = 0; k0 < K; k0 += 32) {
#pragma unroll
        for (int p = 0; p < 2; p++) {
            int i  = p * 256 + t;
            int r  = i >> 2;
            int cg = (i & 3) ^ ((r >> 1) & 3);     // swizzled source chunk
            const __bf16* gA = A + ((size_t)(bm * 128 + r) * K + (size_t)(k0 + cg * 8));
            load_lds16((const void*)gA, (void*)((char*)sA + i * 16));
            const __bf16* gW = W + ((size_t)(bn * 128 + r) * K + (size_t)(k0 + cg * 8));
            load_lds16((const void*)gW, (void*)((char*)sW + i * 16));
        }
        __syncthreads();

        bf16x8 af[4], bfr[4];
#pragma unroll
        for (int i = 0; i < 4; i++) {
            int rowA = wm * 64 + i * 16 + r16;
            int chA  = rowA * 4 + (q ^ ((r16 >> 1) & 3));   // (rowA>>1)&3 == (r16>>1)&3
            af[i]    = *(const bf16x8*)(sA + chA * 8);
            int rowB = wn * 64 + i * 16 + r16;
            int chB  = rowB * 4 + (q ^ ((r16 >> 1) & 3));
            bfr[i]   = *(const bf16x8*)(sW + chB * 8);
        }
        // swapped operands: acc[i][j] rows (q*4+r) = n-dim(j), cols (r16) = m-dim(i)
#pragma unroll
        for (int i = 0; i < 4; i++)
#pragma unroll
            for (int j = 0; j < 4; j++)
                acc[i][j] = __builtin_amdgcn_mfma_f32_16x16x32_bf16(bfr[j], af[i], acc[i][j], 0, 0, 0);
        __syncthreads();
    }

    // lane element (i,j,r):  m = bm*128+wm*64+i*16+r16,  n = bn*128+wn*64+j*16+q*4+r
    if constexpr (MODE == 0) {
#pragma unroll
        for (int j = 0; j < 4; j++) {
            int nb = bn * 128 + wn * 64 + j * 16 + q * 4;
            f32x4 b4 = *(const f32x4*)(bb + nb);
#pragma unroll
            for (int i = 0; i < 4; i++) {
                int m = bm * 128 + wm * 64 + i * 16 + r16;
                bf16x4 o4;
#pragma unroll
                for (int r = 0; r < 4; r++)
                    o4[r] = (__bf16)fmaxf(acc[i][j][r] + b4[r], 0.0f);
                *(bf16x4*)(O + (size_t)m * NH + nb) = o4;
            }
        }
    } else {
#pragma unroll
        for (int i = 0; i < 4; i++) {
            float p0 = 0.f, p1 = 0.f, p2 = 0.f;
#pragma unroll
            for (int j = 0; j < 4; j++) {
                int nb = bn * 128 + wn * 64 + j * 16 + q * 4;
                f32x4 b4 = *(const f32x4*)(bb + nb);
#pragma unroll
                for (int r = 0; r < 4; r++) {
                    float val = fmaxf(acc[i][j][r] + b4[r], 0.0f);
                    const float* w = Wout + (size_t)(nb + r) * NV;
                    p0 += val * w[0]; p1 += val * w[1]; p2 += val * w[2];
                }
            }
            // reduce over the 4 q-lanes (lane bits 4,5) holding the same m
            p0 += __shfl_xor(p0, 16); p0 += __shfl_xor(p0, 32);
            p1 += __shfl_xor(p1, 16); p1 += __shfl_xor(p1, 32);
            p2 += __shfl_xor(p2, 16); p2 += __shfl_xor(p2, 32);
            if (q == 0) {
                int m = bm * 128 + wm * 64 + i * 16 + r16;
                atomicAdd(&out[(size_t)m * NV + 0], p0);
                atomicAdd(&out[(size_t)m * NV + 1], p1);
                atomicAdd(&out[(size_t)m * NV + 2], p2);
            }
        }
    }
}

// ---------------------------------------------------------------------------
extern "C" void kernel_launch(void* const* d_in, const int* in_sizes, int n_in,
                              void* d_out, int out_size, void* d_ws, size_t ws_size,
                              hipStream_t stream) {
    const float* coords     = (const float*)d_in[0];
    const int*   latent_idx = (const int*)d_in[1];
    const float* latents    = (const float*)d_in[2];
    const float* codebooks  = (const float*)d_in[3];
    const float* mod_W      = (const float*)d_in[4];
    const float* mod_b      = (const float*)d_in[5];
    const float* dec_W0     = (const float*)d_in[6];
    const float* dec_b0     = (const float*)d_in[7];
    const float* dec_Wh     = (const float*)d_in[8];
    const float* dec_bh     = (const float*)d_in[9];
    const float* dec_Wout   = (const float*)d_in[10];
    const float* dec_bout   = (const float*)d_in[11];
    float* out = (float*)d_out;

    // ---- workspace layout (fixed part ~8.67 MB) ----
    char* wsb = (char*)d_ws;
    float*  zq  = (float*)(wsb + 0);                       //      256 B
    float*  bb  = (float*)(wsb + 256);                     //   20,480 B
    __bf16* W0T = (__bf16*)(wsb + 20736);                  //  262,144 B  [1024][128]
    __bf16* WhT = (__bf16*)(wsb + 282880);                 // 8,388,608 B [4][1024][1024]
    const size_t fixed_end = 8671488;

    // adaptive chunk: cap 65536 (single chunk, ws ~265 MB), halve until fits;
    // floor 1024 so Mb%8==0. Deterministic in ws_size (capture-safe).
    int Bc = 65536;
    while (Bc > 1024 && fixed_end + 2 * (size_t)Bc * NH * sizeof(__bf16) > ws_size)
        Bc >>= 1;
    int Mb = Bc / 128;

    __bf16* hA = (__bf16*)(wsb + fixed_end);               // [Bc][1024]
    __bf16* hB = hA + (size_t)Bc * NH;                     // [Bc][1024]
    __bf16* pe = hB;   // pe [Bc][128] aliases hB (dead before layer-1 writes hB)

    // ---- one-time (per call) small kernels ----
    vq_kernel<<<1, 1024, 0, stream>>>(latents, latent_idx, codebooks, zq, out);
    betas_kernel<<<20, 256, 0, stream>>>(zq, mod_W, mod_b, dec_b0, dec_bh, bb);
    init_out_kernel<<<(NB * NV) / 256, 256, 0, stream>>>(dec_bout, out);
    prep_kernel<<<dim3(4, 32, 1), dim3(32, 8), 0, stream>>>(dec_W0, W0T, NIN, K0P);
    prep_kernel<<<dim3(32, 32, 4), dim3(32, 8), 0, stream>>>(dec_Wh, WhT, NH, NH);

    // ---- chunked 5-layer MLP, output layer fused into the last GEMM ----
    for (int c0 = 0; c0 < NB; c0 += Bc) {
        pe_kernel<<<(Bc * 128) / 256, 256, 0, stream>>>(coords + (size_t)c0 * NC, pe);
        gemm_kernel<0><<<8 * Mb, 256, 0, stream>>>(
            pe, W0T, bb + 0 * NH, hA, nullptr, nullptr, K0P, Mb);
        gemm_kernel<0><<<8 * Mb, 256, 0, stream>>>(
            hA, WhT + 0 * (size_t)NH * NH, bb + 1 * NH, hB, nullptr, nullptr, NH, Mb);
        gemm_kernel<0><<<8 * Mb, 256, 0, stream>>>(
            hB, WhT + 1 * (size_t)NH * NH, bb + 2 * NH, hA, nullptr, nullptr, NH, Mb);
        gemm_kernel<0><<<8 * Mb, 256, 0, stream>>>(
            hA, WhT + 2 * (size_t)NH * NH, bb + 3 * NH, hB, nullptr, nullptr, NH, Mb);
        gemm_kernel<1><<<8 * Mb, 256, 0, stream>>>(
            hB, WhT + 3 * (size_t)NH * NH, bb + 4 * NH, nullptr,
            dec_Wout, out + (size_t)c0 * NV, NH, Mb);
    }
}

// Round 6
// 944.200 us; speedup vs baseline: 1.2023x; 1.0024x over previous
//
#include <hip/hip_runtime.h>
#include <hip/hip_bf16.h>
#include <stdint.h>

// ---- problem constants ----
#define NB   65536      // batch points
#define NC   2
#define NV   3
#define ND   64
#define NK   1024       // codebook entries
#define NS   4
#define NH   1024
#define NL   5
#define NF   25
#define NIN  102
#define K0P  128        // padded layer-0 K

typedef __bf16 bf16x8 __attribute__((ext_vector_type(8)));
typedef __bf16 bf16x4 __attribute__((ext_vector_type(4)));
typedef float  f32x4  __attribute__((ext_vector_type(4)));

__device__ __forceinline__ void load_lds16(const void* g, void* l) {
    __builtin_amdgcn_global_load_lds(
        (const __attribute__((address_space(1))) void*)g,
        (__attribute__((address_space(3))) void*)l,
        16, 0, 0);
}

// ---------------------------------------------------------------------------
// VQ kernel: single block, 1024 threads (one codebook row per thread).
// ---------------------------------------------------------------------------
__global__ __launch_bounds__(1024) void vq_kernel(
    const float* __restrict__ latents, const int* __restrict__ latent_idx,
    const float* __restrict__ codebooks, float* __restrict__ zq_out,
    float* __restrict__ out) {
    __shared__ float zcur[ND], resid[ND], zqsum[ND], ssq[ND];
    __shared__ float sDw[16];
    __shared__ int   sKw[16];
    __shared__ int   sBest;
    int t = threadIdx.x, lane = t & 63, wv = t >> 6;
    const float* img = latents + (size_t)latent_idx[0] * (NS * ND);
    if (t < ND) { resid[t] = 0.f; zqsum[t] = 0.f; }
    __syncthreads();
    float lossAcc = 0.f;   // thread 0 only
    for (int s = 0; s < NS; s++) {
        if (t < ND) {
            float iv = img[s * ND + t];
            float r  = resid[t] + iv;
            resid[t] = r;
            zcur[t]  = (s == 0) ? iv : (r - zqsum[t]);
        }
        __syncthreads();
        float zz = 0.f;
#pragma unroll
        for (int d = 0; d < ND; d++) { float z = zcur[d]; zz += z * z; }
        const float4* e4 = (const float4*)(codebooks + ((size_t)s * NK + t) * ND);
        float dot = 0.f, ee = 0.f;
#pragma unroll
        for (int i = 0; i < 16; i++) {
            float4 v = e4[i];
            dot += zcur[4 * i + 0] * v.x; dot += zcur[4 * i + 1] * v.y;
            dot += zcur[4 * i + 2] * v.z; dot += zcur[4 * i + 3] * v.w;
            ee  += v.x * v.x; ee += v.y * v.y; ee += v.z * v.z; ee += v.w * v.w;
        }
        float dmin = zz - 2.0f * dot + ee;
        int   kmin = t;
#pragma unroll
        for (int m = 1; m < 64; m <<= 1) {
            float d2 = __shfl_xor(dmin, m);
            int   k2 = __shfl_xor(kmin, m);
            if (d2 < dmin || (d2 == dmin && k2 < kmin)) { dmin = d2; kmin = k2; }
        }
        if (lane == 0) { sDw[wv] = dmin; sKw[wv] = kmin; }
        __syncthreads();
        if (t == 0) {
            float bd = sDw[0]; int bk = sKw[0];
            for (int w = 1; w < 16; w++) {
                float d2 = sDw[w]; int k2 = sKw[w];
                if (d2 < bd || (d2 == bd && k2 < bk)) { bd = d2; bk = k2; }
            }
            sBest = bk;
            out[NB * NV + s] = (float)bk;
        }
        __syncthreads();
        int best = sBest;
        const float* eb = codebooks + ((size_t)s * NK + best) * ND;
        if (t < ND) {
            float zq = eb[t];
            float d  = zq - zcur[t];
            ssq[t]   = d * d;
            zqsum[t] = zqsum[t] + (zq + (zcur[t] - zq));   // z_q_st forward (exact ref arith)
        }
        __syncthreads();
        if (t == 0) {
            float sum = 0.f;
            for (int d = 0; d < ND; d++) sum += ssq[d];
            lossAcc += 0.25f * (sum / (float)ND);
        }
    }
    if (t < ND) zq_out[t] = zqsum[t];
    if (t == 0) out[NB * NV + NS] = lossAcc;
}

// ---------------------------------------------------------------------------
// betas fused with decoder biases
// ---------------------------------------------------------------------------
__global__ __launch_bounds__(256) void betas_kernel(
    const float* __restrict__ zq, const float* __restrict__ mod_W,
    const float* __restrict__ mod_b, const float* __restrict__ b0,
    const float* __restrict__ bh, float* __restrict__ bb) {
    int g = blockIdx.x * 256 + threadIdx.x;   // < 5120
    int l = g >> 10, n = g & 1023;
    float acc = mod_b[g];
    for (int d = 0; d < ND; d++) acc += zq[d] * mod_W[(size_t)(l * ND + d) * NH + n];
    acc += (l == 0) ? b0[n] : bh[(size_t)(l - 1) * NH + n];
    bb[g] = acc;
}

// ---------------------------------------------------------------------------
// out init: values[m][v] = bout[v] (atomic-add target for the fused layer)
// ---------------------------------------------------------------------------
__global__ __launch_bounds__(256) void init_out_kernel(
    const float* __restrict__ bout, float* __restrict__ out) {
    int g = blockIdx.x * 256 + threadIdx.x;   // < NB*NV
    out[g] = bout[g % NV];
}

// ---------------------------------------------------------------------------
// Weight prep: fp32 [Ks][1024] -> bf16 transposed [1024][Kp] (zero-pad k>=Ks)
// ---------------------------------------------------------------------------
__global__ __launch_bounds__(256) void prep_kernel(
    const float* __restrict__ src, __bf16* __restrict__ dst, int Ks, int Kp) {
    __shared__ float tile[32][33];
    src += (size_t)blockIdx.z * Ks * NH;
    dst += (size_t)blockIdx.z * NH * Kp;
    int k0 = blockIdx.x * 32, n0 = blockIdx.y * 32;
    int tx = threadIdx.x, ty = threadIdx.y;   // (32, 8)
    for (int i = 0; i < 4; i++) {
        int k = k0 + ty + i * 8;
        int n = n0 + tx;
        tile[ty + i * 8][tx] = (k < Ks) ? src[(size_t)k * NH + n] : 0.0f;
    }
    __syncthreads();
    for (int i = 0; i < 4; i++) {
        int n = n0 + ty + i * 8;
        int k = k0 + tx;
        dst[(size_t)n * Kp + k] = (__bf16)tile[tx][ty + i * 8];
    }
}

// ---------------------------------------------------------------------------
// Positional encoding for a batch chunk -> bf16 [Bc][128], zero-pad 102..127
// ---------------------------------------------------------------------------
__global__ __launch_bounds__(256) void pe_kernel(
    const float* __restrict__ coords, __bf16* __restrict__ pe) {
    int g = blockIdx.x * 256 + threadIdx.x;   // < Bc*128
    int m = g >> 7, k = g & 127;
    float v = 0.0f;
    if (k < 2) {
        v = coords[m * 2 + k];
    } else if (k < NIN) {
        int u = k - 2;
        int f = u >> 2, r = u & 3;
        float c = coords[m * 2 + (r & 1)];
        float a = c * __builtin_ldexpf(3.14159274101257324f, f);
        v = (r < 2) ? sinf(a) : cosf(a);
    }
    pe[g] = (__bf16)v;
}

// ---------------------------------------------------------------------------
// MFMA GEMM: acc = A[M][K] @ W^T[1024][K] + bb[n], bf16 in, fp32 accumulate.
// 128x128 tile, BK=32, 4 waves (2x2), 16x16x32 bf16 MFMA.
// XCD-residue grid decode (verified R4: FETCH 265->53 MB).
//
// R6 change: LDS DOUBLE-BUFFER with EARLY prefetch. Old loop exposed the full
// L2 latency every iter (loads issued immediately before __syncthreads's
// vmcnt(0) drain). New loop: barrier -> issue tile t+1 into buf^1 -> compute
// tile t from buf. The barrier's vmcnt(0) now waits on loads issued a full
// compute-duration (~600 cyc) earlier -> exposed drain ~0.
// Hazards: prefetch into buf^1 only after the barrier proving all waves
// finished reading buf^1 (lgkmcnt0 drains their ds_reads); next barrier's
// vmcnt(0) drains the prefetch before first read. One barrier per iter.
// ---------------------------------------------------------------------------
template <int MODE>
__global__ __launch_bounds__(256, 4) void gemm_kernel(
    const __bf16* __restrict__ A, const __bf16* __restrict__ W,
    const float* __restrict__ bb, __bf16* __restrict__ O,
    const float* __restrict__ Wout, float* __restrict__ out, int K, int Mb) {
    __shared__ __align__(16) __bf16 sA[2][128 * 32];
    __shared__ __align__(16) __bf16 sW[2][128 * 32];
    int t   = threadIdx.x;
    int fid = blockIdx.x;
    int xcd = fid & 7;
    int j8  = fid >> 3;                 // 0..Mb-1
    int bn  = j8 & 7;                   // fastest within an XCD
    int bm  = xcd * (Mb >> 3) + (j8 >> 3);
    int lane = t & 63, wv = t >> 6;
    int wm   = wv >> 1, wn = wv & 1;
    int q    = lane >> 4, r16 = lane & 15;

    // per-thread staging indices (loop-invariant)
    int si  = t;                        // chunk index 0..255 (+256 for p=1)
    int r0  = si >> 2,        r1  = (si + 256) >> 2;
    int cg0 = (si & 3) ^ ((r0 >> 1) & 3);
    int cg1 = ((si + 256) & 3) ^ ((r1 >> 1) & 3);

    const __bf16* gA0 = A + ((size_t)(bm * 128 + r0) * K + (size_t)(cg0 * 8));
    const __bf16* gA1 = A + ((size_t)(bm * 128 + r1) * K + (size_t)(cg1 * 8));
    const __bf16* gW0 = W + ((size_t)(bn * 128 + r0) * K + (size_t)(cg0 * 8));
    const __bf16* gW1 = W + ((size_t)(bn * 128 + r1) * K + (size_t)(cg1 * 8));

    f32x4 acc[4][4];
    f32x4 zero = {0.f, 0.f, 0.f, 0.f};
    for (int i = 0; i < 4; i++)
        for (int j = 0; j < 4; j++) acc[i][j] = zero;

    int nIter = K >> 5;
    // prologue: stage tile 0 into buf 0
    load_lds16((const void*)gA0, (void*)((char*)sA[0] + si * 16));
    load_lds16((const void*)gW0, (void*)((char*)sW[0] + si * 16));
    load_lds16((const void*)gA1, (void*)((char*)sA[0] + (si + 256) * 16));
    load_lds16((const void*)gW1, (void*)((char*)sW[0] + (si + 256) * 16));

    for (int it = 0; it < nIter; it++) {
        int buf = it & 1;
        __syncthreads();   // vmcnt(0): prefetch into buf landed; lgkmcnt(0): buf^1 reads done
        if (it + 1 < nIter) {
            size_t ko = (size_t)(it + 1) << 5;
            load_lds16((const void*)(gA0 + ko), (void*)((char*)sA[buf ^ 1] + si * 16));
            load_lds16((const void*)(gW0 + ko), (void*)((char*)sW[buf ^ 1] + si * 16));
            load_lds16((const void*)(gA1 + ko), (void*)((char*)sA[buf ^ 1] + (si + 256) * 16));
            load_lds16((const void*)(gW1 + ko), (void*)((char*)sW[buf ^ 1] + (si + 256) * 16));
        }

        bf16x8 af[4], bfr[4];
#pragma unroll
        for (int i = 0; i < 4; i++) {
            int rowA = wm * 64 + i * 16 + r16;
            int chA  = rowA * 4 + (q ^ ((r16 >> 1) & 3));   // (rowA>>1)&3 == (r16>>1)&3
            af[i]    = *(const bf16x8*)(sA[buf] + chA * 8);
            int rowB = wn * 64 + i * 16 + r16;
            int chB  = rowB * 4 + (q ^ ((r16 >> 1) & 3));
            bfr[i]   = *(const bf16x8*)(sW[buf] + chB * 8);
        }
        // swapped operands: acc[i][j] rows (q*4+r) = n-dim(j), cols (r16) = m-dim(i)
#pragma unroll
        for (int i = 0; i < 4; i++)
#pragma unroll
            for (int j = 0; j < 4; j++)
                acc[i][j] = __builtin_amdgcn_mfma_f32_16x16x32_bf16(bfr[j], af[i], acc[i][j], 0, 0, 0);
    }

    // lane element (i,j,r):  m = bm*128+wm*64+i*16+r16,  n = bn*128+wn*64+j*16+q*4+r
    if constexpr (MODE == 0) {
#pragma unroll
        for (int j = 0; j < 4; j++) {
            int nb = bn * 128 + wn * 64 + j * 16 + q * 4;
            f32x4 b4 = *(const f32x4*)(bb + nb);
#pragma unroll
            for (int i = 0; i < 4; i++) {
                int m = bm * 128 + wm * 64 + i * 16 + r16;
                bf16x4 o4;
#pragma unroll
                for (int r = 0; r < 4; r++)
                    o4[r] = (__bf16)fmaxf(acc[i][j][r] + b4[r], 0.0f);
                *(bf16x4*)(O + (size_t)m * NH + nb) = o4;
            }
        }
    } else {
#pragma unroll
        for (int i = 0; i < 4; i++) {
            float p0 = 0.f, p1 = 0.f, p2 = 0.f;
#pragma unroll
            for (int j = 0; j < 4; j++) {
                int nb = bn * 128 + wn * 64 + j * 16 + q * 4;
                f32x4 b4 = *(const f32x4*)(bb + nb);
#pragma unroll
                for (int r = 0; r < 4; r++) {
                    float val = fmaxf(acc[i][j][r] + b4[r], 0.0f);
                    const float* w = Wout + (size_t)(nb + r) * NV;
                    p0 += val * w[0]; p1 += val * w[1]; p2 += val * w[2];
                }
            }
            // reduce over the 4 q-lanes (lane bits 4,5) holding the same m
            p0 += __shfl_xor(p0, 16); p0 += __shfl_xor(p0, 32);
            p1 += __shfl_xor(p1, 16); p1 += __shfl_xor(p1, 32);
            p2 += __shfl_xor(p2, 16); p2 += __shfl_xor(p2, 32);
            if (q == 0) {
                int m = bm * 128 + wm * 64 + i * 16 + r16;
                atomicAdd(&out[(size_t)m * NV + 0], p0);
                atomicAdd(&out[(size_t)m * NV + 1], p1);
                atomicAdd(&out[(size_t)m * NV + 2], p2);
            }
        }
    }
}

// ---------------------------------------------------------------------------
extern "C" void kernel_launch(void* const* d_in, const int* in_sizes, int n_in,
                              void* d_out, int out_size, void* d_ws, size_t ws_size,
                              hipStream_t stream) {
    const float* coords     = (const float*)d_in[0];
    const int*   latent_idx = (const int*)d_in[1];
    const float* latents    = (const float*)d_in[2];
    const float* codebooks  = (const float*)d_in[3];
    const float* mod_W      = (const float*)d_in[4];
    const float* mod_b      = (const float*)d_in[5];
    const float* dec_W0     = (const float*)d_in[6];
    const float* dec_b0     = (const float*)d_in[7];
    const float* dec_Wh     = (const float*)d_in[8];
    const float* dec_bh     = (const float*)d_in[9];
    const float* dec_Wout   = (const float*)d_in[10];
    const float* dec_bout   = (const float*)d_in[11];
    float* out = (float*)d_out;

    // ---- workspace layout (fixed part ~8.67 MB) ----
    char* wsb = (char*)d_ws;
    float*  zq  = (float*)(wsb + 0);                       //      256 B
    float*  bb  = (float*)(wsb + 256);                     //   20,480 B
    __bf16* W0T = (__bf16*)(wsb + 20736);                  //  262,144 B  [1024][128]
    __bf16* WhT = (__bf16*)(wsb + 282880);                 // 8,388,608 B [4][1024][1024]
    const size_t fixed_end = 8671488;

    // adaptive chunk: cap 65536, halve until fits; floor 1024 so Mb%8==0.
    // Deterministic in ws_size -> identical launch sequence (capture-safe).
    int Bc = 65536;
    while (Bc > 1024 && fixed_end + 2 * (size_t)Bc * NH * sizeof(__bf16) > ws_size)
        Bc >>= 1;
    int Mb = Bc / 128;

    __bf16* hA = (__bf16*)(wsb + fixed_end);               // [Bc][1024]
    __bf16* hB = hA + (size_t)Bc * NH;                     // [Bc][1024]
    __bf16* pe = hB;   // pe [Bc][128] aliases hB (dead before layer-1 writes hB)

    // ---- one-time (per call) small kernels ----
    vq_kernel<<<1, 1024, 0, stream>>>(latents, latent_idx, codebooks, zq, out);
    betas_kernel<<<20, 256, 0, stream>>>(zq, mod_W, mod_b, dec_b0, dec_bh, bb);
    init_out_kernel<<<(NB * NV) / 256, 256, 0, stream>>>(dec_bout, out);
    prep_kernel<<<dim3(4, 32, 1), dim3(32, 8), 0, stream>>>(dec_W0, W0T, NIN, K0P);
    prep_kernel<<<dim3(32, 32, 4), dim3(32, 8), 0, stream>>>(dec_Wh, WhT, NH, NH);

    // ---- chunked 5-layer MLP, output layer fused into the last GEMM ----
    for (int c0 = 0; c0 < NB; c0 += Bc) {
        pe_kernel<<<(Bc * 128) / 256, 256, 0, stream>>>(coords + (size_t)c0 * NC, pe);
        gemm_kernel<0><<<8 * Mb, 256, 0, stream>>>(
            pe, W0T, bb + 0 * NH, hA, nullptr, nullptr, K0P, Mb);
        gemm_kernel<0><<<8 * Mb, 256, 0, stream>>>(
            hA, WhT + 0 * (size_t)NH * NH, bb + 1 * NH, hB, nullptr, nullptr, NH, Mb);
        gemm_kernel<0><<<8 * Mb, 256, 0, stream>>>(
            hB, WhT + 1 * (size_t)NH * NH, bb + 2 * NH, hA, nullptr, nullptr, NH, Mb);
        gemm_kernel<0><<<8 * Mb, 256, 0, stream>>>(
            hA, WhT + 2 * (size_t)NH * NH, bb + 3 * NH, hB, nullptr, nullptr, NH, Mb);
        gemm_kernel<1><<<8 * Mb, 256, 0, stream>>>(
            hB, WhT + 3 * (size_t)NH * NH, bb + 4 * NH, nullptr,
            dec_Wout, out + (size_t)c0 * NV, NH, Mb);
    }
}